// Round 1
// baseline (374.742 us; speedup 1.0000x reference)
//
#include <hip/hip_runtime.h>
#include <cstdint>

// ---------------------------------------------------------------------------
// T-LSTM cell, fp32 in/out, via 3-pass split-bf16 MFMA GEMMs.
//   gates = [input|hx] @ [W_ih|W_hh]^T + b_ih + b_hh        (M=4096,N=4096,K=1536)
//   C_ST  = tanh(cx @ W_decomp + b_d); cx_adj = cx + (T-1)*C_ST  (M=4096,N=1024,K=1024)
//   cy = sig(f)*cx_adj + sig(i)*tanh(g); hy = sig(o)*tanh(cy)
// fp32 x = hi + lo (bf16 each); A*B ~= Ah*Bh + Ah*Bl + Al*Bh (fp32 accum).
// ---------------------------------------------------------------------------

typedef __attribute__((ext_vector_type(8))) __bf16 bf16x8;
typedef __attribute__((ext_vector_type(4))) float f32x4;

__device__ __forceinline__ unsigned short f2bf_rn(float f) {
  unsigned int u = __float_as_uint(f);
  unsigned int r = u + 0x7fffu + ((u >> 16) & 1u);
  return (unsigned short)(r >> 16);
}
__device__ __forceinline__ float bf2f(unsigned short h) {
  return __uint_as_float(((unsigned int)h) << 16);
}
__device__ __forceinline__ float sigm_f(float x) {
  return 1.0f / (1.0f + __expf(-x));
}
__device__ __forceinline__ float tanh_f(float x) {
  // robust for large |x|: exp overflows to inf -> 1; underflows to 0 -> -1
  return 1.0f - 2.0f / (__expf(2.0f * x) + 1.0f);
}

__device__ __forceinline__ void gl_lds16(const void* g, void* l) {
  __builtin_amdgcn_global_load_lds(
      (const __attribute__((address_space(1))) void*)g,
      (__attribute__((address_space(3))) void*)l, 16, 0, 0);
}

// --- split a row-major fp32 matrix (optionally concat of two along cols) into
//     hi/lo bf16 buffers. 4 elems/thread; Ka divisible by 4.
__global__ void split_concat_k(const float* __restrict__ a, const float* __restrict__ b,
                               int Ka, int Ktot, long total4,
                               unsigned short* __restrict__ hi,
                               unsigned short* __restrict__ lo) {
  long idx = blockIdx.x * (long)blockDim.x + threadIdx.x;
  if (idx >= total4) return;
  int kcols4 = Ktot >> 2;
  long m = idx / kcols4;
  int k = (int)(idx % kcols4) << 2;
  const float* src = (k < Ka) ? (a + m * (long)Ka + k)
                              : (b + m * (long)(Ktot - Ka) + (k - Ka));
  float4 v = *(const float4*)src;
  unsigned short h0 = f2bf_rn(v.x), h1 = f2bf_rn(v.y), h2 = f2bf_rn(v.z), h3 = f2bf_rn(v.w);
  ushort4 hv; hv.x = h0; hv.y = h1; hv.z = h2; hv.w = h3;
  ushort4 lv;
  lv.x = f2bf_rn(v.x - bf2f(h0));
  lv.y = f2bf_rn(v.y - bf2f(h1));
  lv.z = f2bf_rn(v.z - bf2f(h2));
  lv.w = f2bf_rn(v.w - bf2f(h3));
  *(ushort4*)(hi + m * (long)Ktot + k) = hv;
  *(ushort4*)(lo + m * (long)Ktot + k) = lv;
}

// --- transpose-split W_decomp [N,N] fp32 -> T[n][k]=W[k][n] hi/lo bf16
__global__ void transpose_split_k(const float* __restrict__ W, int Ndim,
                                  unsigned short* __restrict__ Thi,
                                  unsigned short* __restrict__ Tlo) {
  __shared__ float tile[64][65];
  const int bx = blockIdx.x * 64;  // output row block (n)
  const int by = blockIdx.y * 64;  // output col block (k)
  const int tx = threadIdx.x;      // 0..63
  for (int r = threadIdx.y; r < 64; r += 4)
    tile[r][tx] = W[(long)(by + r) * Ndim + bx + tx];
  __syncthreads();
  for (int r = threadIdx.y; r < 64; r += 4) {
    float v = tile[tx][r];  // = W[by+tx][bx+r]
    unsigned short h = f2bf_rn(v);
    long o = (long)(bx + r) * Ndim + by + tx;
    Thi[o] = h;
    Tlo[o] = f2bf_rn(v - bf2f(h));
  }
}

// --- NT GEMM, C[m,n] = sum_k A[m,k]*B[n,k], 3-pass split-bf16.
// 128x128 tile, BK=32, 256 threads (4 waves in 2x2), 64x64 per wave.
// EPI 0: gates  -> C = acc + e0[n] + e1[n]
// EPI 1: decomp -> C = e1[m*N+n] + (T(e2[m])-1)*tanh(acc + e0[n])
template <int EPI>
__global__ __launch_bounds__(256) void gemm3_nt(
    const unsigned short* __restrict__ Ah, const unsigned short* __restrict__ Al,
    const unsigned short* __restrict__ Bh, const unsigned short* __restrict__ Bl,
    int M, int N, int K, float* __restrict__ C,
    const float* __restrict__ e0, const float* __restrict__ e1,
    const float* __restrict__ e2) {
  __shared__ __align__(16) unsigned short sAh[128 * 32];
  __shared__ __align__(16) unsigned short sAl[128 * 32];
  __shared__ __align__(16) unsigned short sBh[128 * 32];
  __shared__ __align__(16) unsigned short sBl[128 * 32];

  const int tid = threadIdx.x;
  const int wave = tid >> 6;
  const int lane = tid & 63;
  const int m0 = blockIdx.y * 128;
  const int n0 = blockIdx.x * 128;
  const int wm = (wave >> 1) * 64;
  const int wn = (wave & 1) * 64;
  const int srow = lane >> 2;        // staging row within 16-row wave chunk
  const int scol = (lane & 3) * 8;   // staging col (bf16 elems), 16B chunk
  const int fm = lane & 15;          // fragment m/n index
  const int fq = lane >> 4;          // fragment k-quad

  f32x4 acc[4][4];
#pragma unroll
  for (int i = 0; i < 4; ++i)
#pragma unroll
    for (int j = 0; j < 4; ++j) acc[i][j] = {0.f, 0.f, 0.f, 0.f};

  for (int kt = 0; kt < K; kt += 32) {
#pragma unroll
    for (int r = 0; r < 2; ++r) {
      const int rowb = r * 64 + wave * 16;  // wave-uniform
      const long gA = (long)(m0 + rowb + srow) * K + kt + scol;
      const long gB = (long)(n0 + rowb + srow) * K + kt + scol;
      const int loff = rowb * 32;  // ushort index; lane*16B appended by HW
      gl_lds16(Ah + gA, sAh + loff);
      gl_lds16(Al + gA, sAl + loff);
      gl_lds16(Bh + gB, sBh + loff);
      gl_lds16(Bl + gB, sBl + loff);
    }
    __syncthreads();
    bf16x8 ah[4], al[4], bh[4], bl[4];
#pragma unroll
    for (int i = 0; i < 4; ++i) {
      const int ao = (wm + i * 16 + fm) * 32 + fq * 8;
      const int bo = (wn + i * 16 + fm) * 32 + fq * 8;
      ah[i] = *(const bf16x8*)(sAh + ao);
      al[i] = *(const bf16x8*)(sAl + ao);
      bh[i] = *(const bf16x8*)(sBh + bo);
      bl[i] = *(const bf16x8*)(sBl + bo);
    }
#pragma unroll
    for (int i = 0; i < 4; ++i)
#pragma unroll
      for (int j = 0; j < 4; ++j) {
        acc[i][j] = __builtin_amdgcn_mfma_f32_16x16x32_bf16(ah[i], bh[j], acc[i][j], 0, 0, 0);
        acc[i][j] = __builtin_amdgcn_mfma_f32_16x16x32_bf16(ah[i], bl[j], acc[i][j], 0, 0, 0);
        acc[i][j] = __builtin_amdgcn_mfma_f32_16x16x32_bf16(al[i], bh[j], acc[i][j], 0, 0, 0);
      }
    __syncthreads();
  }

  // epilogue: C/D layout col = lane&15, row = (lane>>4)*4 + r  [m89-verified]
#pragma unroll
  for (int i = 0; i < 4; ++i) {
#pragma unroll
    for (int j = 0; j < 4; ++j) {
#pragma unroll
      for (int r = 0; r < 4; ++r) {
        const int m = m0 + wm + i * 16 + fq * 4 + r;
        const int n = n0 + wn + j * 16 + fm;
        const float v = acc[i][j][r];
        if (EPI == 0) {
          C[(long)m * N + n] = v + e0[n] + e1[n];
        } else {
          const float g = v + e0[n];
          const float cst = tanh_f(g);
          const float tv = e2[m];
          const float T = (tv != 0.0f) ? (1.0f / tv) : 0.0f;
          C[(long)m * N + n] = e1[(long)m * N + n] + (T - 1.0f) * cst;
        }
      }
    }
  }
}

// --- final elementwise: gates [B,4H] + cx_adj [B,H] -> hy, cy
__global__ void final_k(const float* __restrict__ gates,
                        const float* __restrict__ cxadj,
                        float* __restrict__ out) {
  const long idx = blockIdx.x * 256L + threadIdx.x;  // B*H/4 threads exactly
  const long m = idx >> 8;                           // H/4 = 256 vec4 per row
  const int h = ((int)idx & 255) << 2;
  const float4 ig = *(const float4*)(gates + m * 4096 + h);
  const float4 fg = *(const float4*)(gates + m * 4096 + 1024 + h);
  const float4 cg = *(const float4*)(gates + m * 4096 + 2048 + h);
  const float4 og = *(const float4*)(gates + m * 4096 + 3072 + h);
  const float4 ca = *(const float4*)(cxadj + m * 1024 + h);
  const float* igp = (const float*)&ig;
  const float* fgp = (const float*)&fg;
  const float* cgp = (const float*)&cg;
  const float* ogp = (const float*)&og;
  const float* cap = (const float*)&ca;
  float4 hyv, cyv;
  float* hp = (float*)&hyv;
  float* cp = (float*)&cyv;
#pragma unroll
  for (int c = 0; c < 4; ++c) {
    const float cyc = sigm_f(fgp[c]) * cap[c] + sigm_f(igp[c]) * tanh_f(cgp[c]);
    cp[c] = cyc;
    hp[c] = sigm_f(ogp[c]) * tanh_f(cyc);
  }
  *(float4*)(out + m * 1024 + h) = hyv;
  *(float4*)(out + 4096L * 1024 + m * 1024 + h) = cyv;
}

extern "C" void kernel_launch(void* const* d_in, const int* in_sizes, int n_in,
                              void* d_out, int out_size, void* d_ws, size_t ws_size,
                              hipStream_t stream) {
  const float* input = (const float*)d_in[0];
  const float* t     = (const float*)d_in[1];
  const float* hx    = (const float*)d_in[2];
  const float* cx    = (const float*)d_in[3];
  const float* w_ih  = (const float*)d_in[4];
  const float* w_hh  = (const float*)d_in[5];
  const float* b_ih  = (const float*)d_in[6];
  const float* b_hh  = (const float*)d_in[7];
  const float* Wd    = (const float*)d_in[8];
  const float* b_d   = (const float*)d_in[9];

  const long B = 4096, H = 1024, KX = 1536, NG = 4096;

  char* ws = (char*)d_ws;
  unsigned short* Xhi = (unsigned short*)ws; ws += B * KX * 2;
  unsigned short* Xlo = (unsigned short*)ws; ws += B * KX * 2;
  unsigned short* Whi = (unsigned short*)ws; ws += NG * KX * 2;
  unsigned short* Wlo = (unsigned short*)ws; ws += NG * KX * 2;
  unsigned short* Chi = (unsigned short*)ws; ws += B * H * 2;
  unsigned short* Clo = (unsigned short*)ws; ws += B * H * 2;
  unsigned short* Dhi = (unsigned short*)ws; ws += H * H * 2;
  unsigned short* Dlo = (unsigned short*)ws; ws += H * H * 2;
  float* gates = (float*)ws; ws += B * NG * 4;
  float* cxadj = (float*)ws; ws += B * H * 4;

  // 1-3: hi/lo splits (X = [input|hx], W = [W_ih|W_hh], cx)
  split_concat_k<<<6144, 256, 0, stream>>>(input, hx, 512, 1536, B * KX / 4, Xhi, Xlo);
  split_concat_k<<<6144, 256, 0, stream>>>(w_ih, w_hh, 512, 1536, NG * KX / 4, Whi, Wlo);
  split_concat_k<<<4096, 256, 0, stream>>>(cx, cx, 1024, 1024, B * H / 4, Chi, Clo);
  // 4: transpose-split W_decomp -> [n][k]
  transpose_split_k<<<dim3(16, 16), dim3(64, 4), 0, stream>>>(Wd, 1024, Dhi, Dlo);
  // 5: decomp GEMM + tanh/T epilogue -> cx_adj
  gemm3_nt<1><<<dim3(8, 32), 256, 0, stream>>>(Chi, Clo, Dhi, Dlo,
                                               4096, 1024, 1024, cxadj, b_d, cx, t);
  // 6: gates GEMM + bias epilogue -> gates
  gemm3_nt<0><<<dim3(32, 32), 256, 0, stream>>>(Xhi, Xlo, Whi, Wlo,
                                                4096, 4096, 1536, gates, b_ih, b_hh, nullptr);
  // 7: LSTM pointwise -> hy, cy
  final_k<<<4096, 256, 0, stream>>>(gates, cxadj, (float*)d_out);
}